// Round 3
// baseline (99.356 us; speedup 1.0000x reference)
//
#include <hip/hip_runtime.h>
#include <hip/hip_bf16.h>
#include <cstdint>
#include <cstddef>

#define NB 2048
#define NT 200
#define ND 64
#define NH1 128
#define NH2 64
#define NTP 224   // padded score length

typedef __bf16 bf16x8 __attribute__((ext_vector_type(8)));
typedef float f32x4 __attribute__((ext_vector_type(4)));

#define MFMA16(A, Bv, C) __builtin_amdgcn_mfma_f32_16x16x32_bf16((A), (Bv), (C), 0, 0, 0)

union BF8u { __bf16 b[8]; bf16x8 v; uint4 u4; };

// prep: AbT[j][c] = (W1k - W1d)[c][j]; PT[j][c] = W1prod[c][j]; W2thi[h2][k] = bf16(W2[k][h2])
__global__ void prep_kernel(const float* __restrict__ W1, const float* __restrict__ W2,
                            float* __restrict__ AbT, float* __restrict__ PT,
                            __bf16* __restrict__ W2thi) {
    int tid = blockIdx.x * blockDim.x + threadIdx.x;
    if (tid < NH1 * ND) {
        int j = tid >> 6, c = tid & 63;
        AbT[tid] = W1[(64 + c) * NH1 + j] - W1[(128 + c) * NH1 + j];
        PT[tid]  = W1[(192 + c) * NH1 + j];
        int j2 = tid >> 7, k = tid & 127;
        W2thi[tid] = (__bf16)W2[k * NH2 + j2];
    }
}

// LDS pool layout (22304 B total -> up to 7 blocks/CU by LDS):
//  [0,     4608)  khi  [32][72] bf16        (aliased by SCORES after main loop)
//  [4608,  9216)  klo  [32][72] bf16
//  [9216, 17920)  h1hi [32][136] bf16
//  [17920,21504)  sp   [4][224] f32         (aliased by REDS after softmax)
//  [21504,21760)  q    [64] f32
//  [21760,22272)  qh   [128] f32
//  [22272,22288)  wredm[4]; [22288,22304) wreds[4]
__global__ __launch_bounds__(256, 5)
void attn_main(const float* __restrict__ query, const float* __restrict__ key,
               const float* __restrict__ value, const int* __restrict__ mask,
               const float* __restrict__ W1, const float* __restrict__ b1,
               const float* __restrict__ b2, const float* __restrict__ Wo,
               const float* __restrict__ AbT, const float* __restrict__ PT,
               const __bf16* __restrict__ W2thi,
               float* __restrict__ out)
{
    __shared__ __align__(16) char smem[22304];
    auto KHI  = (__bf16(*)[72])(smem);
    auto KLO  = (__bf16(*)[72])(smem + 4608);
    auto H1HI = (__bf16(*)[136])(smem + 9216);
    auto SP   = (float(*)[NTP])(smem + 17920);
    float* QS    = (float*)(smem + 21504);
    float* QHS   = (float*)(smem + 21760);
    float* WREDM = (float*)(smem + 22272);
    float* WREDS = (float*)(smem + 22288);
    float* SCORES = (float*)(smem);            // alias: k buffers dead after main loop
    auto REDS = (float(*)[68])(smem + 17920);  // alias: sp/q/qh dead after softmax

    const int b = blockIdx.x;
    const int tid = threadIdx.x;
    const int lane = tid & 63;
    const int wave = tid >> 6;
    const int jn = lane & 15;
    const int g8 = (lane >> 4) * 8;

    if (tid < ND) QS[tid] = query[(size_t)b * ND + tid];
    int mk = 0;
    if (tid < NT) mk = mask[(size_t)b * NT + tid];
    __syncthreads();

    // qh = b1 + q . (W1q + W1d)   (coalesced across tid, L2-hot)
    if (tid < NH1) {
        float a = b1[tid];
        #pragma unroll 4
        for (int c = 0; c < ND; ++c)
            a = fmaf(QS[c], W1[c * NH1 + tid] + W1[(128 + c) * NH1 + tid], a);
        QHS[tid] = a;
    }

    // GEMM1 B-fragments: B_b[c][j] = AbT[j][c] + q[c]*PT[j][c], bf16-split, registers.
    // wave owns h1 columns [32*wave, 32*wave+32)
    bf16x8 g1_bhi[2][2], g1_blo[2][2];
    const int jown = wave * 32;
    #pragma unroll
    for (int n = 0; n < 2; ++n) {
        const int j = jown + n * 16 + jn;
        #pragma unroll
        for (int kk = 0; kk < 2; ++kk) {
            const float* ab = AbT + j * ND + kk * 32 + g8;
            const float* pt = PT  + j * ND + kk * 32 + g8;
            float4 a0 = *(const float4*)ab, a1 = *(const float4*)(ab + 4);
            float4 p0 = *(const float4*)pt, p1 = *(const float4*)(pt + 4);
            float va[8] = {a0.x,a0.y,a0.z,a0.w,a1.x,a1.y,a1.z,a1.w};
            float vp[8] = {p0.x,p0.y,p0.z,p0.w,p1.x,p1.y,p1.z,p1.w};
            BF8u vh, vl;
            #pragma unroll
            for (int e = 0; e < 8; ++e) {
                const int c = kk * 32 + g8 + e;
                float v = fmaf(QS[c], vp[e], va[e]);
                __bf16 hi = (__bf16)v;
                vh.b[e] = hi;
                vl.b[e] = (__bf16)(v - (float)hi);
            }
            g1_bhi[n][kk] = vh.v;
            g1_blo[n][kk] = vl.v;
        }
    }
    // GEMM2 B-fragments (W2t, plain bf16), registers; wave owns h2 cols [16w,16w+16)
    bf16x8 g2_whi[4];
    {
        const int j2 = wave * 16 + jn;
        #pragma unroll
        for (int kk = 0; kk < 4; ++kk)
            g2_whi[kk] = *(const bf16x8*)(W2thi + j2 * NH1 + kk * 32 + g8);
    }
    __syncthreads();   // QHS ready; QS reads done
    const float qh0 = QHS[jown + jn];
    const float qh1 = QHS[jown + 16 + jn];
    const float b2j = b2[wave * 16 + jn];
    const float woj = Wo[wave * 16 + jn];

    // ---- main loop: 7 t-tiles of 32 rows, k prefetched one tile ahead ----
    const int r_st = tid >> 3;            // staging row 0..31
    const int c0   = (tid & 7) * 8;       // staging col 0..56
    float4 pf0, pf1;

    auto load_tile = [&](int t0) {
        const int t = t0 + r_st;
        if (t < NT) {
            const float* kp = key + ((size_t)b * NT + t) * ND + c0;
            pf0 = *(const float4*)(kp);
            pf1 = *(const float4*)(kp + 4);
        } else {
            pf0 = float4{0.f, 0.f, 0.f, 0.f};
            pf1 = float4{0.f, 0.f, 0.f, 0.f};
        }
    };
    auto store_tile = [&]() {
        float vals[8] = {pf0.x, pf0.y, pf0.z, pf0.w, pf1.x, pf1.y, pf1.z, pf1.w};
        BF8u ph, pl;
        #pragma unroll
        for (int i = 0; i < 8; ++i) {
            float v = vals[i];
            __bf16 h = (__bf16)v;
            ph.b[i] = h;
            pl.b[i] = (__bf16)(v - (float)h);
        }
        *(uint4*)(&KHI[r_st][c0]) = ph.u4;
        *(uint4*)(&KLO[r_st][c0]) = pl.u4;
    };

    load_tile(0);
    for (int ti = 0; ti < 7; ++ti) {
        store_tile();
        if (ti + 1 < 7) load_tile((ti + 1) * 32);
        __syncthreads();                    // k ready; h1 reads of prev GEMM2 done

        // ---- GEMM1: h1 = relu(qh + k @ B_b); 2 independent 3-chains per (mt,n) ----
        #pragma unroll
        for (int mt = 0; mt < 2; ++mt) {
            const int arow = mt * 16 + jn;
            const bf16x8 a_h0 = *(const bf16x8*)(&KHI[arow][g8]);
            const bf16x8 a_h1 = *(const bf16x8*)(&KHI[arow][32 + g8]);
            const bf16x8 a_l0 = *(const bf16x8*)(&KLO[arow][g8]);
            const bf16x8 a_l1 = *(const bf16x8*)(&KLO[arow][32 + g8]);
            #pragma unroll
            for (int n = 0; n < 2; ++n) {
                f32x4 acA = {0.f, 0.f, 0.f, 0.f};
                f32x4 acB = {0.f, 0.f, 0.f, 0.f};
                acA = MFMA16(a_h0, g1_bhi[n][0], acA);
                acB = MFMA16(a_h1, g1_bhi[n][1], acB);
                acA = MFMA16(a_l0, g1_bhi[n][0], acA);
                acB = MFMA16(a_l1, g1_bhi[n][1], acB);
                acA = MFMA16(a_h0, g1_blo[n][0], acA);
                acB = MFMA16(a_h1, g1_blo[n][1], acB);
                const float qhj = (n == 0) ? qh0 : qh1;
                const int j = jown + n * 16 + jn;
                #pragma unroll
                for (int r = 0; r < 4; ++r) {
                    const int tl = mt * 16 + (lane >> 4) * 4 + r;
                    float v = fmaxf(acA[r] + acB[r] + qhj, 0.f);
                    H1HI[tl][j] = (__bf16)v;
                }
            }
        }
        __syncthreads();                    // h1 ready

        // ---- GEMM2 + fused score: s_t = relu(h1@W2 + b2) . Wo ----
        const int t0 = ti * 32;
        #pragma unroll
        for (int mt = 0; mt < 2; ++mt) {
            const int arow = mt * 16 + jn;
            bf16x8 ahi[4];
            #pragma unroll
            for (int kk = 0; kk < 4; ++kk)
                ahi[kk] = *(const bf16x8*)(&H1HI[arow][kk * 32 + g8]);
            f32x4 cA = {0.f, 0.f, 0.f, 0.f};
            f32x4 cB = {0.f, 0.f, 0.f, 0.f};
            cA = MFMA16(ahi[0], g2_whi[0], cA);
            cB = MFMA16(ahi[1], g2_whi[1], cB);
            cA = MFMA16(ahi[2], g2_whi[2], cA);
            cB = MFMA16(ahi[3], g2_whi[3], cB);
            #pragma unroll
            for (int r = 0; r < 4; ++r) {
                float v = fmaxf(cA[r] + cB[r] + b2j, 0.f);
                float contrib = v * woj;
                contrib += __shfl_xor(contrib, 1);
                contrib += __shfl_xor(contrib, 2);
                contrib += __shfl_xor(contrib, 4);
                contrib += __shfl_xor(contrib, 8);
                if (jn == 0)
                    SP[wave][t0 + mt * 16 + (lane >> 4) * 4 + r] = contrib;
            }
        }
    }
    __syncthreads();   // all SP stores visible; k buffers dead -> SCORES usable

    // ---- value prefetch (first two rows per thread) issued under softmax ----
    const int dq = tid & 15;
    const int tg = tid >> 4;
    const float* vbase = value + (size_t)b * NT * ND + dq * 4;
    const float4 vv0 = *(const float4*)(vbase + (size_t)tg * ND);
    const float4 vv1 = *(const float4*)(vbase + (size_t)(tg + 16) * ND);

    // ---- mask + softmax (fp32) ----
    float sc = -1e30f;
    if (tid < NT && mk != 0)
        sc = SP[0][tid] + SP[1][tid] + SP[2][tid] + SP[3][tid];
    float m = sc;
    #pragma unroll
    for (int off = 32; off > 0; off >>= 1) m = fmaxf(m, __shfl_xor(m, off));
    if (lane == 0) WREDM[wave] = m;
    __syncthreads();
    m = fmaxf(fmaxf(WREDM[0], WREDM[1]), fmaxf(WREDM[2], WREDM[3]));
    const float e = (tid < NT && mk != 0) ? __expf(sc - m) : 0.f;
    SCORES[tid] = e;
    float es = e;
    #pragma unroll
    for (int off = 32; off > 0; off >>= 1) es += __shfl_xor(es, off);
    if (lane == 0) WREDS[wave] = es;
    __syncthreads();   // SCORES + WREDS ready; SP dead -> REDS usable
    const float inv = 1.f / (WREDS[0] + WREDS[1] + WREDS[2] + WREDS[3]);

    // ---- out = (attn @ V) * inv ----
    {
        const float s0 = SCORES[tg], s1 = SCORES[tg + 16];
        float a0 = fmaf(s1, vv1.x, s0 * vv0.x);
        float a1 = fmaf(s1, vv1.y, s0 * vv0.y);
        float a2 = fmaf(s1, vv1.z, s0 * vv0.z);
        float a3 = fmaf(s1, vv1.w, s0 * vv0.w);
        for (int t = tg + 32; t < NT; t += 16) {
            const float at = SCORES[t];
            const float4 v4 = *(const float4*)(vbase + (size_t)t * ND);
            a0 = fmaf(at, v4.x, a0); a1 = fmaf(at, v4.y, a1);
            a2 = fmaf(at, v4.z, a2); a3 = fmaf(at, v4.w, a3);
        }
        REDS[tg][dq*4+0] = a0; REDS[tg][dq*4+1] = a1;
        REDS[tg][dq*4+2] = a2; REDS[tg][dq*4+3] = a3;
    }
    __syncthreads();
    if (tid < ND) {
        float s = 0.f;
        #pragma unroll
        for (int g = 0; g < 16; ++g) s += REDS[g][tid];
        out[(size_t)b * ND + tid] = s * inv;
    }
}

extern "C" void kernel_launch(void* const* d_in, const int* in_sizes, int n_in,
                              void* d_out, int out_size, void* d_ws, size_t ws_size,
                              hipStream_t stream) {
    const float* query = (const float*)d_in[0];
    const float* key   = (const float*)d_in[1];
    const float* value = (const float*)d_in[2];
    const int*   maskp = (const int*)d_in[3];
    const float* W1    = (const float*)d_in[4];
    const float* b1    = (const float*)d_in[5];
    const float* W2    = (const float*)d_in[6];
    const float* b2    = (const float*)d_in[7];
    const float* Wo    = (const float*)d_in[8];
    float* out = (float*)d_out;

    float* AbT = (float*)d_ws;                      // 128*64 f32 (32 KB)
    float* PT  = AbT + NH1 * ND;                    // 128*64 f32 (32 KB)
    __bf16* W2thi = (__bf16*)(PT + NH1 * ND);       // 64*128 bf16 (16 KB)

    prep_kernel<<<32, 256, 0, stream>>>(W1, W2, AbT, PT, W2thi);
    attn_main<<<NB, 256, 0, stream>>>(query, key, value, maskp, W1, b1, b2, Wo,
                                      AbT, PT, W2thi, out);
}